// Round 1
// baseline (801.837 us; speedup 1.0000x reference)
//
#include <hip/hip_runtime.h>
#include <stdint.h>

// ---------------------------------------------------------------------------
// Lingunet5Filter: 5x dynamic 1x1 conv (per-sample weight) + instance norm
// on levels 1-4.  Per (b, level): Y[o,s] = sum_c F[b,o,c] * X[b,c,s], then
// (Y - mean_s Y) * rsqrt(var_s Y + 1e-5) for levels 1-4.
//
// Design (round 1 baseline):
//  - bf16 MFMA (16x16x32) GEMM per sample: block tile M=128(o) x N=128(s) x
//    K=128(c), 4 waves in 2x2, wave does 4x4 tiles of 16x16, fp32 accum.
//  - Conv epilogue: wave-reduce Sum(y), Sum(y^2) per (b,o) -> global atomics
//    (stats pass is free).  y stored bf16 to workspace (if ws fits) else
//    fp32 to d_out.
//  - Norm kernel: y -> (y-mean)*rstd, fp32 to d_out.  Memory-bound.
// ---------------------------------------------------------------------------

typedef __bf16 bf16x8 __attribute__((ext_vector_type(8)));
typedef float f32x4 __attribute__((ext_vector_type(4)));
typedef unsigned short u16;
typedef u16 u16x4 __attribute__((ext_vector_type(4)));
typedef u16 u16x8 __attribute__((ext_vector_type(8)));

__device__ __forceinline__ u16 f2bf(float f) {
    uint32_t u = __builtin_bit_cast(uint32_t, f);
    u += 0x7fffu + ((u >> 16) & 1u);
    return (u16)(u >> 16);
}
__device__ __forceinline__ float bf2f(u16 h) {
    return __builtin_bit_cast(float, (uint32_t)h << 16);
}

#define LDSP 136   // 128 bf16 + 8 pad: keeps ds_read_b128 16B-aligned, rows 4 banks apart

template<bool YBF16>
__global__ __launch_bounds__(256, 2)
void conv_kernel(const float* __restrict__ x, const float* __restrict__ fw,
                 float* __restrict__ out, u16* __restrict__ ybf,
                 float* __restrict__ ysum, float* __restrict__ ysq,
                 int HW, int ntiles, int do_stats)
{
    __shared__ u16 ldsF[128 * LDSP];   // F[b]: [o][c], c-contiguous
    __shared__ u16 ldsX[128 * LDSP];   // X tile: [c][s], s-contiguous

    const int t  = threadIdx.x;
    const int b  = blockIdx.x / ntiles;
    const int st = blockIdx.x % ntiles;

    const float* fb = fw + (size_t)b * (128 * 128);
    const float* xb = x  + (size_t)b * 128 * HW + st * 128;

    // ---- stage F (128x128 fp32 -> bf16 LDS), fully coalesced float4 ----
    #pragma unroll
    for (int i = 0; i < 16; ++i) {
        int fi  = t + 256 * i;       // float4 index over [128][32]
        int row = fi >> 5;           // o
        int c4  = fi & 31;
        f32x4 v = *reinterpret_cast<const f32x4*>(fb + row * 128 + c4 * 4);
        u16x4 h = { f2bf(v[0]), f2bf(v[1]), f2bf(v[2]), f2bf(v[3]) };
        *reinterpret_cast<u16x4*>(&ldsF[row * LDSP + c4 * 4]) = h;
    }
    // ---- stage X tile (128c x 128s fp32 -> bf16 LDS) ----
    #pragma unroll
    for (int i = 0; i < 16; ++i) {
        int fi  = t + 256 * i;
        int row = fi >> 5;           // c
        int c4  = fi & 31;
        int s   = c4 * 4;            // s within tile
        if (st * 128 + s < HW) {     // only level 5 (HW=64) trips this
            f32x4 v = *reinterpret_cast<const f32x4*>(xb + (size_t)row * HW + s);
            u16x4 h = { f2bf(v[0]), f2bf(v[1]), f2bf(v[2]), f2bf(v[3]) };
            *reinterpret_cast<u16x4*>(&ldsX[row * LDSP + c4 * 4]) = h;
        }
    }
    __syncthreads();

    const int lane = t & 63;
    const int w    = t >> 6;
    const int wm   = w >> 1;     // wave's M half (o)
    const int wn   = w & 1;      // wave's N half (s)
    const int m16  = lane & 15;
    const int quad = lane >> 4;

    f32x4 acc[4][4] = {};

    #pragma unroll
    for (int ks = 0; ks < 4; ++ks) {           // K = 128 in 4 steps of 32
        const int kbase = ks * 32 + quad * 8;
        bf16x8 afr[4], bfr[4];
        #pragma unroll
        for (int i = 0; i < 4; ++i) {          // A[m][k]: contiguous b128
            int row = wm * 64 + i * 16 + m16;  // o
            afr[i] = *reinterpret_cast<const bf16x8*>(&ldsF[row * LDSP + kbase]);
        }
        #pragma unroll
        for (int j = 0; j < 4; ++j) {          // B[k][n]: gather across c rows
            int col = wn * 64 + j * 16 + m16;  // s within tile
            u16x8 tmp;
            #pragma unroll
            for (int e = 0; e < 8; ++e)
                tmp[e] = ldsX[(kbase + e) * LDSP + col];
            bfr[j] = __builtin_bit_cast(bf16x8, tmp);
        }
        #pragma unroll
        for (int i = 0; i < 4; ++i)
            #pragma unroll
            for (int j = 0; j < 4; ++j)
                acc[i][j] = __builtin_amdgcn_mfma_f32_16x16x32_bf16(afr[i], bfr[j], acc[i][j], 0, 0, 0);
    }

    // ---- epilogue: store y (bf16->ws or fp32->out) + per-(b,o) stats ----
    const size_t outbase = (size_t)b * 128 * HW;
    #pragma unroll
    for (int i = 0; i < 4; ++i) {
        #pragma unroll
        for (int r = 0; r < 4; ++r) {
            const int o = wm * 64 + i * 16 + quad * 4 + r;   // C/D row = quad*4+reg
            float s1 = 0.f, s2 = 0.f;
            #pragma unroll
            for (int j = 0; j < 4; ++j) {
                float v = acc[i][j][r];
                int s = st * 128 + wn * 64 + j * 16 + m16;   // C/D col = lane&15
                if (s < HW) {
                    size_t idx = outbase + (size_t)o * HW + s;
                    if constexpr (YBF16) ybf[idx] = f2bf(v);
                    else                 out[idx] = v;
                }
                s1 += v; s2 += v * v;
            }
            if (do_stats) {
                // reduce across the 16 lanes of this output row (xor<16 stays in quad)
                #pragma unroll
                for (int off = 8; off; off >>= 1) {
                    s1 += __shfl_xor(s1, off, 64);
                    s2 += __shfl_xor(s2, off, 64);
                }
                if (m16 == 0) {
                    atomicAdd(&ysum[b * 128 + o], s1);
                    atomicAdd(&ysq [b * 128 + o], s2);
                }
            }
        }
    }
}

template<bool INBF16>
__global__ void norm_kernel(const u16* __restrict__ ybf, float* __restrict__ out,
                            const float* __restrict__ ysum, const float* __restrict__ ysq,
                            int HW, int n4)
{
    const int hw4 = HW >> 2;
    const float invHW = 1.0f / (float)HW;   // HW is a power of two: exact
    for (int idx = blockIdx.x * blockDim.x + threadIdx.x; idx < n4;
         idx += gridDim.x * blockDim.x) {
        int row = idx / hw4;                 // b*128 + o
        float mean = ysum[row] * invHW;
        float var  = ysq[row] * invHW - mean * mean;
        float rstd = rsqrtf(var + 1e-5f);
        f32x4 v;
        if constexpr (INBF16) {
            u16x4 h = reinterpret_cast<const u16x4*>(ybf)[idx];
            v[0] = bf2f(h[0]); v[1] = bf2f(h[1]); v[2] = bf2f(h[2]); v[3] = bf2f(h[3]);
        } else {
            v = reinterpret_cast<const f32x4*>(out)[idx];
        }
        v[0] = (v[0] - mean) * rstd;
        v[1] = (v[1] - mean) * rstd;
        v[2] = (v[2] - mean) * rstd;
        v[3] = (v[3] - mean) * rstd;
        reinterpret_cast<f32x4*>(out)[idx] = v;
    }
}

extern "C" void kernel_launch(void* const* d_in, const int* in_sizes, int n_in,
                              void* d_out, int out_size, void* d_ws, size_t ws_size,
                              hipStream_t stream)
{
    (void)in_sizes; (void)n_in; (void)out_size;
    // setup_inputs dict order: x1,l1fs,x2,l2fs,...
    const float* x[5]  = {(const float*)d_in[0], (const float*)d_in[2], (const float*)d_in[4],
                          (const float*)d_in[6], (const float*)d_in[8]};
    const float* fl[5] = {(const float*)d_in[1], (const float*)d_in[3], (const float*)d_in[5],
                          (const float*)d_in[7], (const float*)d_in[9]};
    float* out = (float*)d_out;

    const int HW[5] = {128 * 128, 64 * 64, 32 * 32, 16 * 16, 8 * 8};
    size_t off[5];
    off[0] = 0;
    for (int l = 1; l < 5; ++l) off[l] = off[l - 1] + (size_t)32 * 128 * HW[l - 1];

    float* stats = (float*)d_ws;
    const size_t STATS_BYTES = 4 * 8192 * sizeof(float);   // per level: 4096 sums + 4096 sumsq

    // bf16-y scratch layout (levels 1-4) after stats
    size_t ybf_off[4];
    size_t need = STATS_BYTES;
    for (int l = 0; l < 4; ++l) { ybf_off[l] = need; need += (size_t)32 * 128 * HW[l] * sizeof(u16); }
    const bool usebf = (ws_size >= need);

    hipMemsetAsync(d_ws, 0, STATS_BYTES, stream);

    for (int l = 0; l < 5; ++l) {
        int ntiles = (HW[l] + 127) / 128;
        int grid = 32 * ntiles;
        float* ysum = stats + (l < 4 ? l : 0) * 8192;
        float* ysq  = ysum + 4096;
        if (l < 4 && usebf) {
            u16* ybf = (u16*)((char*)d_ws + ybf_off[l]);
            conv_kernel<true><<<grid, 256, 0, stream>>>(x[l], fl[l], out + off[l], ybf,
                                                        ysum, ysq, HW[l], ntiles, 1);
        } else {
            conv_kernel<false><<<grid, 256, 0, stream>>>(x[l], fl[l], out + off[l], nullptr,
                                                         ysum, ysq, HW[l], ntiles, l < 4 ? 1 : 0);
        }
    }
    for (int l = 0; l < 4; ++l) {
        int n4 = 32 * 128 * HW[l] / 4;
        int blocks = (n4 + 255) / 256;
        if (blocks > 2048) blocks = 2048;
        float* ysum = stats + l * 8192;
        float* ysq  = ysum + 4096;
        if (usebf) {
            const u16* ybf = (const u16*)((char*)d_ws + ybf_off[l]);
            norm_kernel<true><<<blocks, 256, 0, stream>>>(ybf, out + off[l], ysum, ysq, HW[l], n4);
        } else {
            norm_kernel<false><<<blocks, 256, 0, stream>>>(nullptr, out + off[l], ysum, ysq, HW[l], n4);
        }
    }
}